// Round 13
// baseline (94.468 us; speedup 1.0000x reference)
//
#include <hip/hip_runtime.h>

#define IWE_H 480
#define IWE_W 640
#define IWE_HW (IWE_H * IWE_W)
#define FLOW_SCALING 128.0f
#define MAX_TS 1.0f

#define BAND_H 2
#define NBANDS (IWE_H / BAND_H)        // 240 bands of 2 rows
#define CAP 8192                       // slots per (batch,band); ~2x uniform mean 4167
#define OVF_CAP 65536
#define SCAT_BLOCK 256
#define EV_PER_THREAD 8
#define CHUNK (SCAT_BLOCK * EV_PER_THREAD)   // 2048 events per block
#define SCAN_N 256
#define QMAX 512.0f
#define WSCALE (512.f * 512.f)

// recB (u32): [0:2) rr2  [2:12) xi+1  [12:21) qy  [21:30) qx  [30] pol

static __device__ inline float4 nt_load4(const float4* p) {
    union { double d[2]; float4 v; } u;
    const double* q = (const double*)p;
    u.d[0] = __builtin_nontemporal_load(q);
    u.d[1] = __builtin_nontemporal_load(q + 1);
    return u.v;
}
static __device__ inline float2 nt_load2(const float2* p) {
    union { double d; float2 v; } u;
    u.d = __builtin_nontemporal_load((const double*)p);
    return u.v;
}

// wave-level inclusive scan over 64 lanes
static __device__ inline unsigned wave_scan(unsigned v) {
    #pragma unroll
    for (int off = 1; off < 64; off <<= 1) {
        unsigned u = __shfl_up(v, off, 64);
        if ((threadIdx.x & 63) >= off) v += u;
    }
    return v;
}

// ---------------- pass 0: pack flow to float2 + zero cursors/ovf_cnt ----------------
__global__ void flow_pack(const float* __restrict__ flow, float2* __restrict__ flowp,
                          unsigned* __restrict__ wszero, int total)
{
    int i = blockIdx.x * blockDim.x + threadIdx.x;
    if (i < 3072) wszero[i] = 0u;                         // cursors + ovf_cnt region
    if (i >= total) return;
    int b = i / IWE_HW, lin = i % IWE_HW;
    const float* fb = flow + (size_t)b * 2 * IWE_HW;
    flowp[i] = make_float2(fb[lin], fb[IWE_HW + lin]);    // (fx, fy)
}

// ---------------- pass 1: fused gather+warp+bin ----------------
__global__ __launch_bounds__(SCAT_BLOCK, 8)
void ev_scatter(const float* __restrict__ ev, const float2* __restrict__ flowp,
                unsigned* __restrict__ recs, unsigned* __restrict__ cursors,
                unsigned* __restrict__ ovf_cnt, float2* __restrict__ ovf,
                int N, int C, int lpb)   // lpb = XCD lanes/batch (0 => 2D grid)
{
    __shared__ unsigned s_cnt[SCAN_N];
    __shared__ unsigned s_scan[SCAN_N];
    __shared__ unsigned s_wsum[4];
    __shared__ unsigned s_base[NBANDS];
    __shared__ unsigned s_rec[CHUNK];                     // 8 KB
    __shared__ unsigned short s_band[CHUNK];              // 4 KB

    int b, chunk;
    if (lpb) {                                    // XCD-pinned: blockIdx.x&7 ~ XCD
        int lane = blockIdx.x & 7;
        b = lane / lpb;
        chunk = ((int)(blockIdx.x >> 3)) * lpb + (lane % lpb);
    } else { b = blockIdx.y; chunk = blockIdx.x; }
    const int base_e = chunk * CHUNK;
    const bool live_chunk = (chunk < C);

    for (int i = threadIdx.x; i < SCAN_N; i += SCAT_BLOCK) s_cnt[i] = 0;
    __syncthreads();

    int      lin0[EV_PER_THREAD];                 // pixel index, -1 = dead
    unsigned meta[EV_PER_THREAD];                 // (tsq<<1)|pol
    float2   fl[EV_PER_THREAD];
    int      bands[EV_PER_THREAD];
    unsigned ranks[EV_PER_THREAD];
    unsigned recw[EV_PER_THREAD];

    const float2* fb = flowp + (size_t)b * IWE_HW;
    const float4* evb = reinterpret_cast<const float4*>(ev) + (size_t)b * N;

    // phase A: stream events; compress to 2 regs/event
    #pragma unroll
    for (int i = 0; i < EV_PER_THREAD; ++i) {
        int e = base_e + i * SCAT_BLOCK + threadIdx.x;
        lin0[i] = -1;
        if (live_chunk && e < N) {
            float4 ee = nt_load4(evb + e);                // (ts, y, x, p)
            lin0[i] = (int)(ee.y * (float)IWE_W + ee.z);  // exact: < 2^24
            unsigned tsq = (unsigned)(ee.x * 1048576.0f); // 20-bit ts
            meta[i] = (tsq << 1) | (ee.w > 0.f ? 1u : 0u);
        }
    }
    // phase B: independent flow gathers, NT (bypass L1 allocation: hit rate ~0)
    #pragma unroll
    for (int i = 0; i < EV_PER_THREAD; ++i) {
        fl[i] = (lin0[i] >= 0) ? nt_load2(fb + lin0[i]) : make_float2(0.f, 0.f);
    }
    // phase C: warp, quantize, rank
    #pragma unroll
    for (int i = 0; i < EV_PER_THREAD; ++i) {
        bands[i] = -1;
        if (lin0[i] < 0) continue;
        int y = lin0[i] / IWE_W;
        int x = lin0[i] - y * IWE_W;
        float ts = (float)(meta[i] >> 1) * (1.f / 1048576.f);
        unsigned pol = meta[i] & 1u;
        float dt = (MAX_TS - ts) * FLOW_SCALING;
        float wy = (float)y + dt * fl[i].y;
        float wx = (float)x + dt * fl[i].x;
        float ty = floorf(wy), lx = floorf(wx);
        int ity = (int)ty, ixl = (int)lx;
        if (ity < -1 || ity > IWE_H - 1 || ixl < -1 || ixl > IWE_W - 1) continue;
        unsigned qy = min((unsigned)((wy - ty) * QMAX + 0.5f), 511u);
        unsigned qx = min((unsigned)((wx - lx) * QMAX + 0.5f), 511u);
        int band = ity >> 1; if (band < 0) band = 0;
        unsigned rr2 = (unsigned)(ity - band * 2 + 1);    // 0,1,2
        recw[i] = rr2 | ((unsigned)(ixl + 1) << 2) | (qy << 12) | (qx << 21) | (pol << 30);
        bands[i] = band;
        ranks[i] = atomicAdd(&s_cnt[band], 1u);
    }
    __syncthreads();

    // 256-wide inclusive scan: per-wave shfl scan + cross-wave combine
    {
        int t = threadIdx.x;
        unsigned sc = wave_scan(s_cnt[t]);
        if ((t & 63) == 63) s_wsum[t >> 6] = sc;
        __syncthreads();
        unsigned offs = 0;
        #pragma unroll
        for (int w = 0; w < 4; ++w) if (w < (t >> 6)) offs += s_wsum[w];
        s_scan[t] = sc + offs;
        if (t < NBANDS) {
            unsigned c = s_cnt[t];
            s_base[t] = c ? atomicAdd(&cursors[b * NBANDS + t], c) : 0u;
        }
    }
    __syncthreads();

    // scatter records into LDS in band order
    #pragma unroll
    for (int i = 0; i < EV_PER_THREAD; ++i) {
        if (bands[i] < 0) continue;
        unsigned pos = s_scan[bands[i]] - s_cnt[bands[i]] + ranks[i];
        if (pos < CHUNK) {
            s_rec[pos]  = recw[i];
            s_band[pos] = (unsigned short)bands[i];
        }
    }
    __syncthreads();

    // coalesced global write
    unsigned total = s_scan[SCAN_N - 1];
    if (total > CHUNK) total = CHUNK;
    for (unsigned idx = threadIdx.x; idx < total; idx += SCAT_BLOCK) {
        unsigned band = s_band[idx];
        unsigned local = idx - (s_scan[band] - s_cnt[band]);
        unsigned slot = s_base[band] + local;
        int bin = b * NBANDS + (int)band;
        if (slot < CAP) {
            recs[(size_t)bin * CAP + slot] = s_rec[idx];
        } else {
            unsigned o = atomicAdd(ovf_cnt, 1u);
            if (o < OVF_CAP) ovf[o] = make_float2(__uint_as_float(s_rec[idx]), (float)bin);
        }
    }
}

// ---------------- pass 2: per-band integer accumulation (u64 LDS atomics) ----------
__global__ __launch_bounds__(512)
void band_splat(const unsigned* __restrict__ recs, const unsigned* __restrict__ cursors,
                float* __restrict__ out, float* __restrict__ halo)
{
    __shared__ unsigned long long tile[2 * BAND_H * IWE_W];   // 20.5 KB
    const int bg = blockIdx.x;
    const int band = bg % NBANDS;
    const int b = bg / NBANDS;
    const int y0g = band * BAND_H;

    for (int i = threadIdx.x; i < 2 * BAND_H * IWE_W; i += 512) tile[i] = 0ull;
    __syncthreads();

    unsigned cnt = cursors[bg]; if (cnt > CAP) cnt = CAP;
    const unsigned* r = recs + (size_t)bg * CAP;

    for (unsigned i = threadIdx.x; i < cnt; i += 512) {
        unsigned rec = r[i];
        unsigned rr2 = rec & 3u;
        int xi1      = (int)((rec >> 2) & 1023u);             // = xi+1 in [0,640]
        unsigned qy  = (rec >> 12) & 511u;
        unsigned qx  = (rec >> 21) & 511u;
        int plane    = (rec >> 30) & 1u ? 0 : 1;              // pos=plane0
        unsigned wy0 = 512u - qy, wy1 = qy;
        unsigned wx0 = 512u - qx, wx1 = qx;
        unsigned long long vL, vR;
        int entry;
        if (rr2 == 0u) {                                      // ity == -1: row 0 only
            entry = 0;
            vL = (unsigned long long)(wy1 * wx0);
            vR = (unsigned long long)(wy1 * wx1);
        } else {
            entry = (int)rr2 - 1;
            bool hiOK = (y0g + entry + 1) < IWE_H;
            vL = (unsigned long long)(wy0 * wx0) |
                 ((unsigned long long)(hiOK ? wy1 * wx0 : 0u) << 32);
            vR = (unsigned long long)(wy0 * wx1) |
                 ((unsigned long long)(hiOK ? wy1 * wx1 : 0u) << 32);
        }
        unsigned long long* pl = tile + (plane * BAND_H + entry) * IWE_W;
        if (xi1 >= 1     && vL) atomicAdd(&pl[xi1 - 1], vL);
        if (xi1 <  IWE_W && vR) atomicAdd(&pl[xi1],     vR);
    }
    __syncthreads();

    for (int j = threadIdx.x; j < 2 * BAND_H * IWE_W; j += 512) {
        int plane = j / (BAND_H * IWE_W);
        int rem   = j % (BAND_H * IWE_W);
        int rr = rem / IWE_W, x = rem % IWE_W;
        unsigned v = (unsigned)(tile[(plane * BAND_H + rr) * IWE_W + x] & 0xffffffffu);
        if (rr > 0) v += (unsigned)(tile[(plane * BAND_H + rr - 1) * IWE_W + x] >> 32);
        out[(((size_t)b * 2 + plane) * IWE_H + (y0g + rr)) * IWE_W + x] =
            (float)v * (1.f / WSCALE);
    }
    for (int j = threadIdx.x; j < 2 * IWE_W; j += 512) {
        int plane = j / IWE_W, x = j % IWE_W;
        unsigned v = (unsigned)(tile[(plane * BAND_H + BAND_H - 1) * IWE_W + x] >> 32);
        halo[((size_t)bg * 2 + plane) * IWE_W + x] = (float)v * (1.f / WSCALE);
    }
}

// ---------------- pass 3: add halo rows (unique targets, no atomics) ----------------
__global__ void halo_add(const float* __restrict__ halo, float* __restrict__ out, int B)
{
    int t = blockIdx.x * blockDim.x + threadIdx.x;
    int total = B * (NBANDS - 1) * 2 * IWE_W;
    if (t >= total) return;
    int x = t % IWE_W; int rest = t / IWE_W;
    int plane = rest & 1; rest >>= 1;
    int bi = rest % (NBANDS - 1);
    int b  = rest / (NBANDS - 1);
    int bg = b * NBANDS + bi;
    float v = halo[((size_t)bg * 2 + plane) * IWE_W + x];
    size_t oi = (((size_t)b * 2 + plane) * IWE_H + (size_t)(bi + 1) * BAND_H) * IWE_W + x;
    out[oi] += v;
}

// ---------------- pass 4: overflow fallback (expected empty) ----------------
__global__ void ovf_splat(const float2* __restrict__ ovf, const unsigned* __restrict__ ovf_cnt,
                          float* __restrict__ out)
{
    unsigned cnt = *ovf_cnt; if (cnt > OVF_CAP) cnt = OVF_CAP;
    for (unsigned i = blockIdx.x * blockDim.x + threadIdx.x; i < cnt;
         i += gridDim.x * blockDim.x) {
        float2 e = ovf[i];
        unsigned rec = __float_as_uint(e.x);
        int bg = (int)e.y;
        int band = bg % NBANDS, b = bg / NBANDS;
        int y0g = band * BAND_H;
        unsigned rr2 = rec & 3u;
        int xi1      = (int)((rec >> 2) & 1023u);
        float fy = (float)((rec >> 12) & 511u) * (1.f / QMAX);
        float fx = (float)((rec >> 21) & 511u) * (1.f / QMAX);
        int plane    = (rec >> 30) & 1u ? 0 : 1;
        int ity = y0g + (int)rr2 - 1;
        float* pl = out + ((size_t)b * 2 + plane) * IWE_HW;
        bool xl = xi1 >= 1, xr = xi1 < IWE_W;
        if (ity >= 0 && ity < IWE_H) {
            if (xl) atomicAdd(pl + ity * IWE_W + xi1 - 1, (1.f - fy) * (1.f - fx));
            if (xr) atomicAdd(pl + ity * IWE_W + xi1,     (1.f - fy) * fx);
        }
        if (ity + 1 >= 0 && ity + 1 < IWE_H) {
            if (xl) atomicAdd(pl + (ity + 1) * IWE_W + xi1 - 1, fy * (1.f - fx));
            if (xr) atomicAdd(pl + (ity + 1) * IWE_W + xi1,     fy * fx);
        }
    }
}

// ---------------- fallback: direct atomic splat ----------------
__global__ void iwe_direct_kernel(const float* __restrict__ ev, const float* __restrict__ flow,
                                  float* __restrict__ out, int N)
{
    int n = blockIdx.x * blockDim.x + threadIdx.x;
    int b = blockIdx.y;
    if (n >= N) return;
    float4 e = *reinterpret_cast<const float4*>(ev + ((size_t)b * N + n) * 4);
    float ts = e.x, y = e.y, x = e.z, p = e.w;
    const float* fb = flow + (size_t)b * 2 * IWE_HW;
    int lin0 = (int)(y * (float)IWE_W + x);
    float fx = fb[lin0], fy = fb[IWE_HW + lin0];
    float dt = (MAX_TS - ts) * FLOW_SCALING;
    float wy = y + dt * fy, wx = x + dt * fx;
    float ty = floorf(wy), lx = floorf(wx);
    float fyf = wy - ty, fxf = wx - lx;
    int iy = (int)ty, ix = (int)lx;
    float* plane = out + ((size_t)b * 2 + (p > 0.f ? 0 : 1)) * IWE_HW;
    if ((unsigned)iy < IWE_H) {
        if ((unsigned)ix       < IWE_W) atomicAdd(plane + iy * IWE_W + ix,     (1.f-fyf)*(1.f-fxf));
        if ((unsigned)(ix + 1) < IWE_W) atomicAdd(plane + iy * IWE_W + ix + 1, (1.f-fyf)*fxf);
    }
    if ((unsigned)(iy + 1) < IWE_H) {
        if ((unsigned)ix       < IWE_W) atomicAdd(plane + (iy+1) * IWE_W + ix,     fyf*(1.f-fxf));
        if ((unsigned)(ix + 1) < IWE_W) atomicAdd(plane + (iy+1) * IWE_W + ix + 1, fyf*fxf);
    }
}

extern "C" void kernel_launch(void* const* d_in, const int* in_sizes, int n_in,
                              void* d_out, int out_size, void* d_ws, size_t ws_size,
                              hipStream_t stream) {
    const float* ev   = (const float*)d_in[0];   // [B,N,4]
    const float* flow = (const float*)d_in[1];   // [B,2,H,W]
    float* out = (float*)d_out;                  // [B,2,H,W]

    int B = in_sizes[1] / (2 * IWE_HW);
    int N = in_sizes[0] / (4 * B);

    // workspace layout (cursors+ovf_cnt zeroed by flow_pack, first 3072 u32)
    size_t off_cursors = 0;                                   // B*240 u32
    size_t off_ovfcnt  = 8192;
    size_t off_halo    = 12288;
    size_t halo_bytes  = (size_t)B * NBANDS * 2 * IWE_W * 4;
    size_t off_flowp   = (off_halo + halo_bytes + 255) & ~(size_t)255;
    size_t flowp_bytes = (size_t)B * IWE_HW * 8;
    size_t off_recs    = (off_flowp + flowp_bytes + 255) & ~(size_t)255;
    size_t recs_bytes  = (size_t)B * NBANDS * CAP * 4;
    size_t off_ovf     = off_recs + recs_bytes;
    size_t need        = off_ovf + (size_t)OVF_CAP * 8;

    if ((size_t)B * NBANDS * 4 > 8192 || need > ws_size) {
        hipMemsetAsync(d_out, 0, (size_t)out_size * sizeof(float), stream);
        dim3 grid((N + 255) / 256, B);
        iwe_direct_kernel<<<grid, dim3(256), 0, stream>>>(ev, flow, out, N);
        return;
    }

    char* ws = (char*)d_ws;
    unsigned* cursors = (unsigned*)(ws + off_cursors);
    unsigned* ovf_cnt = (unsigned*)(ws + off_ovfcnt);
    float*    halo    = (float*)(ws + off_halo);
    float2*   flowp   = (float2*)(ws + off_flowp);
    unsigned* recs    = (unsigned*)(ws + off_recs);
    float2*   ovf     = (float2*)(ws + off_ovf);

    int ftotal = B * IWE_HW;
    flow_pack<<<dim3((ftotal + 255) / 256), dim3(256), 0, stream>>>(
        flow, flowp, (unsigned*)d_ws, ftotal);

    int C = (N + CHUNK - 1) / CHUNK;
    if (B <= 8 && (8 % B) == 0) {
        int lpb = 8 / B;
        int iters = (C + lpb - 1) / lpb;
        ev_scatter<<<dim3(8 * iters), dim3(SCAT_BLOCK), 0, stream>>>(
            ev, flowp, recs, cursors, ovf_cnt, ovf, N, C, lpb);
    } else {
        ev_scatter<<<dim3(C, B), dim3(SCAT_BLOCK), 0, stream>>>(
            ev, flowp, recs, cursors, ovf_cnt, ovf, N, C, 0);
    }

    band_splat<<<dim3(B * NBANDS), dim3(512), 0, stream>>>(recs, cursors, out, halo);

    int htotal = B * (NBANDS - 1) * 2 * IWE_W;
    halo_add<<<dim3((htotal + 255) / 256), dim3(256), 0, stream>>>(halo, out, B);

    ovf_splat<<<dim3(32), dim3(256), 0, stream>>>(ovf, ovf_cnt, out);
}

// Round 14
// 66.611 us; speedup vs baseline: 1.4182x; 1.4182x over previous
//
#include <hip/hip_runtime.h>

#define IWE_H 480
#define IWE_W 640
#define IWE_HW (IWE_H * IWE_W)
#define FLOW_SCALING 128.0f
#define MAX_TS 1.0f

#define BAND_H 2
#define NBANDS (IWE_H / BAND_H)        // 240 bands of 2 rows
#define CAP 8192                       // slots per (batch,band); ~2x uniform mean 4167
#define OVF_CAP 65536
#define SCAT_BLOCK 256
#define EV_PER_THREAD 16
#define CHUNK (SCAT_BLOCK * EV_PER_THREAD)   // 4096 events per block
#define SCAN_N 256
#define QMAX 512.0f
#define WSCALE (512.f * 512.f)

// recB (u32): [0:2) rr2  [2:12) xi+1  [12:21) qy  [21:30) qx  [30] pol

static __device__ inline float4 nt_load4(const float4* p) {
    union { double d[2]; float4 v; } u;
    const double* q = (const double*)p;
    u.d[0] = __builtin_nontemporal_load(q);
    u.d[1] = __builtin_nontemporal_load(q + 1);
    return u.v;
}

// ---------------- pass 0: pack flow to float2 + zero cursors/ovf_cnt ----------------
__global__ void flow_pack(const float* __restrict__ flow, float2* __restrict__ flowp,
                          unsigned* __restrict__ wszero, int total)
{
    int i = blockIdx.x * blockDim.x + threadIdx.x;
    if (i < 3072) wszero[i] = 0u;                         // cursors + ovf_cnt region
    if (i >= total) return;
    int b = i / IWE_HW, lin = i % IWE_HW;
    const float* fb = flow + (size_t)b * 2 * IWE_HW;
    flowp[i] = make_float2(fb[lin], fb[IWE_HW + lin]);    // (fx, fy)
}

// ---------------- pass 1: fused gather+warp+bin, 16 gathers in flight ----------------
__global__ __launch_bounds__(SCAT_BLOCK)
void ev_scatter(const float* __restrict__ ev, const float2* __restrict__ flowp,
                unsigned* __restrict__ recs, unsigned* __restrict__ cursors,
                unsigned* __restrict__ ovf_cnt, float2* __restrict__ ovf,
                int N, int C, int lpb)   // lpb = XCD lanes/batch (0 => 2D grid)
{
    __shared__ unsigned s_cnt[SCAN_N];
    __shared__ unsigned s_scan[SCAN_N];
    __shared__ unsigned s_base[NBANDS];
    __shared__ unsigned s_rec[CHUNK];                     // 16 KB
    __shared__ unsigned short s_band[CHUNK];              // 8 KB

    int b, chunk;
    if (lpb) {                                    // XCD-pinned: blockIdx.x&7 ~ XCD
        int lane = blockIdx.x & 7;
        b = lane / lpb;
        chunk = ((int)(blockIdx.x >> 3)) * lpb + (lane % lpb);
    } else { b = blockIdx.y; chunk = blockIdx.x; }
    const int base_e = chunk * CHUNK;
    const bool live_chunk = (chunk < C);

    for (int i = threadIdx.x; i < SCAN_N; i += SCAT_BLOCK) s_cnt[i] = 0;
    __syncthreads();

    int      lin0[EV_PER_THREAD];                 // pixel index, -1 = dead
    unsigned meta[EV_PER_THREAD];                 // (tsq<<1)|pol, tsq = ts*2^20
    float2   fl[EV_PER_THREAD];
    int      bands[EV_PER_THREAD];
    unsigned ranks[EV_PER_THREAD];
    unsigned recw[EV_PER_THREAD];

    const float2* fb = flowp + (size_t)b * IWE_HW;
    const float4* evb = reinterpret_cast<const float4*>(ev) + (size_t)b * N;

    // phase A: stream events; compress to 2 regs/event immediately (keeps VGPR low)
    #pragma unroll
    for (int i = 0; i < EV_PER_THREAD; ++i) {
        int e = base_e + i * SCAT_BLOCK + threadIdx.x;
        lin0[i] = -1;
        if (live_chunk && e < N) {
            float4 ee = nt_load4(evb + e);                // (ts, y, x, p)
            lin0[i] = (int)(ee.y * (float)IWE_W + ee.z);  // exact: < 2^24
            unsigned tsq = (unsigned)(ee.x * 1048576.0f); // 20-bit ts (err 1.2e-4 px)
            meta[i] = (tsq << 1) | (ee.w > 0.f ? 1u : 0u);
        }
    }
    // phase B: 16 independent flow gathers in flight
    #pragma unroll
    for (int i = 0; i < EV_PER_THREAD; ++i) {
        fl[i] = (lin0[i] >= 0) ? fb[lin0[i]] : make_float2(0.f, 0.f);
    }
    // phase C: warp, quantize, rank
    #pragma unroll
    for (int i = 0; i < EV_PER_THREAD; ++i) {
        bands[i] = -1;
        if (lin0[i] < 0) continue;
        int y = lin0[i] / IWE_W;                          // magic-mul div
        int x = lin0[i] - y * IWE_W;
        float ts = (float)(meta[i] >> 1) * (1.f / 1048576.f);
        unsigned pol = meta[i] & 1u;
        float dt = (MAX_TS - ts) * FLOW_SCALING;
        float wy = (float)y + dt * fl[i].y;
        float wx = (float)x + dt * fl[i].x;
        float ty = floorf(wy), lx = floorf(wx);
        int ity = (int)ty, ixl = (int)lx;
        if (ity < -1 || ity > IWE_H - 1 || ixl < -1 || ixl > IWE_W - 1) continue;
        unsigned qy = min((unsigned)((wy - ty) * QMAX + 0.5f), 511u);
        unsigned qx = min((unsigned)((wx - lx) * QMAX + 0.5f), 511u);
        int band = ity >> 1; if (band < 0) band = 0;
        unsigned rr2 = (unsigned)(ity - band * 2 + 1);    // 0,1,2
        recw[i] = rr2 | ((unsigned)(ixl + 1) << 2) | (qy << 12) | (qx << 21) | (pol << 30);
        bands[i] = band;
        ranks[i] = atomicAdd(&s_cnt[band], 1u);
    }
    __syncthreads();

    // block-local inclusive prefix over bands (Hillis-Steele)
    {
        int t = threadIdx.x;
        s_scan[t] = s_cnt[t];
        __syncthreads();
        for (int off = 1; off < SCAN_N; off <<= 1) {
            unsigned u = (t >= off) ? s_scan[t - off] : 0u;
            __syncthreads();
            s_scan[t] += u;
            __syncthreads();
        }
        if (t < NBANDS) {
            unsigned c = s_cnt[t];
            s_base[t] = c ? atomicAdd(&cursors[b * NBANDS + t], c) : 0u;
        }
    }
    __syncthreads();

    // scatter records into LDS in band order
    #pragma unroll
    for (int i = 0; i < EV_PER_THREAD; ++i) {
        if (bands[i] < 0) continue;
        unsigned pos = s_scan[bands[i]] - s_cnt[bands[i]] + ranks[i];
        if (pos < CHUNK) {
            s_rec[pos]  = recw[i];
            s_band[pos] = (unsigned short)bands[i];
        }
    }
    __syncthreads();

    // coalesced global write: consecutive idx -> consecutive slots per band segment
    unsigned total = s_scan[SCAN_N - 1];
    if (total > CHUNK) total = CHUNK;
    for (unsigned idx = threadIdx.x; idx < total; idx += SCAT_BLOCK) {
        unsigned band = s_band[idx];
        unsigned local = idx - (s_scan[band] - s_cnt[band]);
        unsigned slot = s_base[band] + local;
        int bin = b * NBANDS + (int)band;
        if (slot < CAP) {
            recs[(size_t)bin * CAP + slot] = s_rec[idx];
        } else {
            unsigned o = atomicAdd(ovf_cnt, 1u);
            if (o < OVF_CAP) ovf[o] = make_float2(__uint_as_float(s_rec[idx]), (float)bin);
        }
    }
}

// ---------------- pass 2: per-band integer accumulation (u64 LDS atomics) ----------
__global__ __launch_bounds__(512)
void band_splat(const unsigned* __restrict__ recs, const unsigned* __restrict__ cursors,
                float* __restrict__ out, float* __restrict__ halo)
{
    __shared__ unsigned long long tile[2 * BAND_H * IWE_W];   // 20.5 KB
    const int bg = blockIdx.x;
    const int band = bg % NBANDS;
    const int b = bg / NBANDS;
    const int y0g = band * BAND_H;

    for (int i = threadIdx.x; i < 2 * BAND_H * IWE_W; i += 512) tile[i] = 0ull;
    __syncthreads();

    unsigned cnt = cursors[bg]; if (cnt > CAP) cnt = CAP;
    const unsigned* r = recs + (size_t)bg * CAP;

    for (unsigned i = threadIdx.x; i < cnt; i += 512) {
        unsigned rec = r[i];
        unsigned rr2 = rec & 3u;
        int xi1      = (int)((rec >> 2) & 1023u);             // = xi+1 in [0,640]
        unsigned qy  = (rec >> 12) & 511u;
        unsigned qx  = (rec >> 21) & 511u;
        int plane    = (rec >> 30) & 1u ? 0 : 1;              // pos=plane0
        unsigned wy0 = 512u - qy, wy1 = qy;
        unsigned wx0 = 512u - qx, wx1 = qx;
        unsigned long long vL, vR;
        int entry;
        if (rr2 == 0u) {                                      // ity == -1: row 0 only
            entry = 0;
            vL = (unsigned long long)(wy1 * wx0);
            vR = (unsigned long long)(wy1 * wx1);
        } else {
            entry = (int)rr2 - 1;
            bool hiOK = (y0g + entry + 1) < IWE_H;
            vL = (unsigned long long)(wy0 * wx0) |
                 ((unsigned long long)(hiOK ? wy1 * wx0 : 0u) << 32);
            vR = (unsigned long long)(wy0 * wx1) |
                 ((unsigned long long)(hiOK ? wy1 * wx1 : 0u) << 32);
        }
        unsigned long long* pl = tile + (plane * BAND_H + entry) * IWE_W;
        if (xi1 >= 1     && vL) atomicAdd(&pl[xi1 - 1], vL);
        if (xi1 <  IWE_W && vR) atomicAdd(&pl[xi1],     vR);
    }
    __syncthreads();

    for (int j = threadIdx.x; j < 2 * BAND_H * IWE_W; j += 512) {
        int plane = j / (BAND_H * IWE_W);
        int rem   = j % (BAND_H * IWE_W);
        int rr = rem / IWE_W, x = rem % IWE_W;
        unsigned v = (unsigned)(tile[(plane * BAND_H + rr) * IWE_W + x] & 0xffffffffu);
        if (rr > 0) v += (unsigned)(tile[(plane * BAND_H + rr - 1) * IWE_W + x] >> 32);
        out[(((size_t)b * 2 + plane) * IWE_H + (y0g + rr)) * IWE_W + x] =
            (float)v * (1.f / WSCALE);
    }
    for (int j = threadIdx.x; j < 2 * IWE_W; j += 512) {
        int plane = j / IWE_W, x = j % IWE_W;
        unsigned v = (unsigned)(tile[(plane * BAND_H + BAND_H - 1) * IWE_W + x] >> 32);
        halo[((size_t)bg * 2 + plane) * IWE_W + x] = (float)v * (1.f / WSCALE);
    }
}

// ---------------- pass 3: add halo rows (unique targets, no atomics) ----------------
__global__ void halo_add(const float* __restrict__ halo, float* __restrict__ out, int B)
{
    int t = blockIdx.x * blockDim.x + threadIdx.x;
    int total = B * (NBANDS - 1) * 2 * IWE_W;
    if (t >= total) return;
    int x = t % IWE_W; int rest = t / IWE_W;
    int plane = rest & 1; rest >>= 1;
    int bi = rest % (NBANDS - 1);
    int b  = rest / (NBANDS - 1);
    int bg = b * NBANDS + bi;
    float v = halo[((size_t)bg * 2 + plane) * IWE_W + x];
    size_t oi = (((size_t)b * 2 + plane) * IWE_H + (size_t)(bi + 1) * BAND_H) * IWE_W + x;
    out[oi] += v;
}

// ---------------- pass 4: overflow fallback (expected empty) ----------------
__global__ void ovf_splat(const float2* __restrict__ ovf, const unsigned* __restrict__ ovf_cnt,
                          float* __restrict__ out)
{
    unsigned cnt = *ovf_cnt; if (cnt > OVF_CAP) cnt = OVF_CAP;
    for (unsigned i = blockIdx.x * blockDim.x + threadIdx.x; i < cnt;
         i += gridDim.x * blockDim.x) {
        float2 e = ovf[i];
        unsigned rec = __float_as_uint(e.x);
        int bg = (int)e.y;
        int band = bg % NBANDS, b = bg / NBANDS;
        int y0g = band * BAND_H;
        unsigned rr2 = rec & 3u;
        int xi1      = (int)((rec >> 2) & 1023u);
        float fy = (float)((rec >> 12) & 511u) * (1.f / QMAX);
        float fx = (float)((rec >> 21) & 511u) * (1.f / QMAX);
        int plane    = (rec >> 30) & 1u ? 0 : 1;
        int ity = y0g + (int)rr2 - 1;
        float* pl = out + ((size_t)b * 2 + plane) * IWE_HW;
        bool xl = xi1 >= 1, xr = xi1 < IWE_W;
        if (ity >= 0 && ity < IWE_H) {
            if (xl) atomicAdd(pl + ity * IWE_W + xi1 - 1, (1.f - fy) * (1.f - fx));
            if (xr) atomicAdd(pl + ity * IWE_W + xi1,     (1.f - fy) * fx);
        }
        if (ity + 1 >= 0 && ity + 1 < IWE_H) {
            if (xl) atomicAdd(pl + (ity + 1) * IWE_W + xi1 - 1, fy * (1.f - fx));
            if (xr) atomicAdd(pl + (ity + 1) * IWE_W + xi1,     fy * fx);
        }
    }
}

// ---------------- fallback: direct atomic splat ----------------
__global__ void iwe_direct_kernel(const float* __restrict__ ev, const float* __restrict__ flow,
                                  float* __restrict__ out, int N)
{
    int n = blockIdx.x * blockDim.x + threadIdx.x;
    int b = blockIdx.y;
    if (n >= N) return;
    float4 e = *reinterpret_cast<const float4*>(ev + ((size_t)b * N + n) * 4);
    float ts = e.x, y = e.y, x = e.z, p = e.w;
    const float* fb = flow + (size_t)b * 2 * IWE_HW;
    int lin0 = (int)(y * (float)IWE_W + x);
    float fx = fb[lin0], fy = fb[IWE_HW + lin0];
    float dt = (MAX_TS - ts) * FLOW_SCALING;
    float wy = y + dt * fy, wx = x + dt * fx;
    float ty = floorf(wy), lx = floorf(wx);
    float fyf = wy - ty, fxf = wx - lx;
    int iy = (int)ty, ix = (int)lx;
    float* plane = out + ((size_t)b * 2 + (p > 0.f ? 0 : 1)) * IWE_HW;
    if ((unsigned)iy < IWE_H) {
        if ((unsigned)ix       < IWE_W) atomicAdd(plane + iy * IWE_W + ix,     (1.f-fyf)*(1.f-fxf));
        if ((unsigned)(ix + 1) < IWE_W) atomicAdd(plane + iy * IWE_W + ix + 1, (1.f-fyf)*fxf);
    }
    if ((unsigned)(iy + 1) < IWE_H) {
        if ((unsigned)ix       < IWE_W) atomicAdd(plane + (iy+1) * IWE_W + ix,     fyf*(1.f-fxf));
        if ((unsigned)(ix + 1) < IWE_W) atomicAdd(plane + (iy+1) * IWE_W + ix + 1, fyf*fxf);
    }
}

extern "C" void kernel_launch(void* const* d_in, const int* in_sizes, int n_in,
                              void* d_out, int out_size, void* d_ws, size_t ws_size,
                              hipStream_t stream) {
    const float* ev   = (const float*)d_in[0];   // [B,N,4]
    const float* flow = (const float*)d_in[1];   // [B,2,H,W]
    float* out = (float*)d_out;                  // [B,2,H,W]

    int B = in_sizes[1] / (2 * IWE_HW);
    int N = in_sizes[0] / (4 * B);

    // workspace layout (cursors+ovf_cnt zeroed by flow_pack, first 3072 u32)
    size_t off_cursors = 0;                                   // B*240 u32
    size_t off_ovfcnt  = 8192;
    size_t off_halo    = 12288;
    size_t halo_bytes  = (size_t)B * NBANDS * 2 * IWE_W * 4;
    size_t off_flowp   = (off_halo + halo_bytes + 255) & ~(size_t)255;
    size_t flowp_bytes = (size_t)B * IWE_HW * 8;
    size_t off_recs    = (off_flowp + flowp_bytes + 255) & ~(size_t)255;
    size_t recs_bytes  = (size_t)B * NBANDS * CAP * 4;
    size_t off_ovf     = off_recs + recs_bytes;
    size_t need        = off_ovf + (size_t)OVF_CAP * 8;

    if ((size_t)B * NBANDS * 4 > 8192 || need > ws_size) {
        hipMemsetAsync(d_out, 0, (size_t)out_size * sizeof(float), stream);
        dim3 grid((N + 255) / 256, B);
        iwe_direct_kernel<<<grid, dim3(256), 0, stream>>>(ev, flow, out, N);
        return;
    }

    char* ws = (char*)d_ws;
    unsigned* cursors = (unsigned*)(ws + off_cursors);
    unsigned* ovf_cnt = (unsigned*)(ws + off_ovfcnt);
    float*    halo    = (float*)(ws + off_halo);
    float2*   flowp   = (float2*)(ws + off_flowp);
    unsigned* recs    = (unsigned*)(ws + off_recs);
    float2*   ovf     = (float2*)(ws + off_ovf);

    int ftotal = B * IWE_HW;
    flow_pack<<<dim3((ftotal + 255) / 256), dim3(256), 0, stream>>>(
        flow, flowp, (unsigned*)d_ws, ftotal);

    int C = (N + CHUNK - 1) / CHUNK;
    if (B <= 8 && (8 % B) == 0) {
        int lpb = 8 / B;
        int iters = (C + lpb - 1) / lpb;
        ev_scatter<<<dim3(8 * iters), dim3(SCAT_BLOCK), 0, stream>>>(
            ev, flowp, recs, cursors, ovf_cnt, ovf, N, C, lpb);
    } else {
        ev_scatter<<<dim3(C, B), dim3(SCAT_BLOCK), 0, stream>>>(
            ev, flowp, recs, cursors, ovf_cnt, ovf, N, C, 0);
    }

    band_splat<<<dim3(B * NBANDS), dim3(512), 0, stream>>>(recs, cursors, out, halo);

    int htotal = B * (NBANDS - 1) * 2 * IWE_W;
    halo_add<<<dim3((htotal + 255) / 256), dim3(256), 0, stream>>>(halo, out, B);

    ovf_splat<<<dim3(32), dim3(256), 0, stream>>>(ovf, ovf_cnt, out);
}